// Round 1
// baseline (318.716 us; speedup 1.0000x reference)
//
#include <hip/hip_runtime.h>
#include <hip/hip_bf16.h>

#define ALPHA 0.2f
#define LOG2E 1.44269504088896340736f

typedef float  f32x4 __attribute__((ext_vector_type(4)));
typedef float  f32x2 __attribute__((ext_vector_type(2)));
typedef int    i32x4 __attribute__((ext_vector_type(4)));
typedef int    i32x2 __attribute__((ext_vector_type(2)));

static __device__ __forceinline__ void mfma_bf16_16x16x32(f32x4& c, i32x4 a, i32x4 b) {
  asm("v_mfma_f32_16x16x32_bf16 %0, %1, %2, %0" : "+v"(c) : "v"(a), "v"(b));
}

static __device__ __forceinline__ unsigned short f2bf(float x) {
  __hip_bfloat16 b = __float2bfloat16(x);
  return *reinterpret_cast<unsigned short*>(&b);
}
static __device__ __forceinline__ unsigned int packbf2(float x, float y) {
  return (unsigned int)f2bf(x) | ((unsigned int)f2bf(y) << 16);
}
static __device__ __forceinline__ float dot4(f32x4 a, f32x4 b) {
  return a.x*b.x + a.y*b.y + a.z*b.z + a.w*b.w;
}

// ---------------- Kernel A: Wt[f][k] = bf16(W[k][f]);  v1 = W@a1, v2 = W@a2 ----------------
__global__ __launch_bounds__(256) void k_setup(const float* __restrict__ W, const float* __restrict__ a,
                                               unsigned short* __restrict__ wt,
                                               float* __restrict__ v1, float* __restrict__ v2) {
  const int bid = blockIdx.x, tid = threadIdx.x;
  __shared__ float S[32][33];
  if (bid < 256) {               // 16x16 tiles of 32x32: transpose W -> Wt (bf16)
    const int k0 = (bid >> 4) * 32, f0 = (bid & 15) * 32;
    const int r = tid >> 5, c = tid & 31;
    #pragma unroll
    for (int rr = r; rr < 32; rr += 8) S[rr][c] = W[(size_t)(k0 + rr) * 512 + f0 + c];
    __syncthreads();
    #pragma unroll
    for (int rr = r; rr < 32; rr += 8) wt[(size_t)(f0 + rr) * 512 + k0 + c] = f2bf(S[c][rr]);
  } else {                       // 128 blocks x 4 waves: one wave per k-row of W
    const int kk = (bid - 256) * 4 + (tid >> 6);
    const int l = tid & 63;
    const float* wr = W + (size_t)kk * 512 + l * 8;
    f32x4 w0 = *(const f32x4*)(wr),           w1 = *(const f32x4*)(wr + 4);
    f32x4 p0 = *(const f32x4*)(a + l*8),      p1 = *(const f32x4*)(a + l*8 + 4);
    f32x4 q0 = *(const f32x4*)(a + 512 + l*8),q1 = *(const f32x4*)(a + 512 + l*8 + 4);
    float s1 = dot4(w0,p0) + dot4(w1,p1);
    float s2 = dot4(w0,q0) + dot4(w1,q1);
    #pragma unroll
    for (int off = 1; off < 64; off <<= 1) { s1 += __shfl_xor(s1, off); s2 += __shfl_xor(s2, off); }
    if (l == 0) { v1[kk] = s1; v2[kk] = s2; }
  }
}

// ---------------- Kernel B: ei[row]=log2e*(h.v1), ej[row]=log2e*(h.v2) (exact f32 path) ----
__global__ __launch_bounds__(256) void k_ei_ej(const float* __restrict__ h,
                                               const float* __restrict__ v1, const float* __restrict__ v2,
                                               float* __restrict__ ei, float* __restrict__ ej) {
  const int row = blockIdx.x * 4 + (threadIdx.x >> 6);
  const int l = threadIdx.x & 63;
  const float* hr = h + (size_t)row * 512 + l * 8;
  f32x4 x0 = *(const f32x4*)hr,            x1 = *(const f32x4*)(hr + 4);
  f32x4 a0 = *(const f32x4*)(v1 + l*8),    a1 = *(const f32x4*)(v1 + l*8 + 4);
  f32x4 b0 = *(const f32x4*)(v2 + l*8),    b1 = *(const f32x4*)(v2 + l*8 + 4);
  float s1 = dot4(x0,a0) + dot4(x1,a1);
  float s2 = dot4(x0,b0) + dot4(x1,b1);
  #pragma unroll
  for (int off = 1; off < 64; off <<= 1) { s1 += __shfl_xor(s1, off); s2 += __shfl_xor(s2, off); }
  if (l == 0) { ei[row] = s1 * LOG2E; ej[row] = s2 * LOG2E; }
}

// ---------------- Kernel C: WhT[b][f][n] = bf16( (h@W)[b][n][f] ) -------------------------
// 256 blocks, 512 thr (8 waves). BM=64 rows, BN=512 (all f), BK=32.
// A (h tile) staged f32->bf16 in LDS [2][kc=4][64][8]; B-frags direct from Wt (L2) w/ prefetch.
__global__ __launch_bounds__(512, 2) void k_gemm_wh(const float* __restrict__ h,
                                                    const unsigned short* __restrict__ wt,
                                                    unsigned short* __restrict__ whT) {
  const int tid = threadIdx.x;
  const int w = tid >> 6, l = tid & 63;
  const int i0g = blockIdx.x * 64;
  const int b = i0g >> 11;
  const int nb = i0g & 2047;
  __shared__ __align__(16) unsigned short Alds[2][4][64][8];

  const int sr = tid >> 3;          // 0..63  staging row
  const int sc = (tid & 7) * 4;     // 0..28  staging k
  const float* hrow = h + (size_t)(i0g + sr) * 512 + sc;

  const int fl = l & 15, kq = l >> 4;
  const unsigned short* wp[4];
  #pragma unroll
  for (int cf = 0; cf < 4; ++cf) {
    const int f = w*64 + cf*16 + fl;
    wp[cf] = wt + (size_t)f * 512 + kq * 8;
  }

  f32x4 acc[4][4];
  #pragma unroll
  for (int i = 0; i < 4; ++i)
    #pragma unroll
    for (int j = 0; j < 4; ++j) acc[i][j] = (f32x4){0.f,0.f,0.f,0.f};

  f32x4 hcur = *(const f32x4*)hrow;
  i32x4 bcur[4];
  #pragma unroll
  for (int cf = 0; cf < 4; ++cf) bcur[cf] = *(const i32x4*)(wp[cf]);

  for (int s = 0; s < 16; ++s) {
    const unsigned int lo = packbf2(hcur.x, hcur.y), hi = packbf2(hcur.z, hcur.w);
    *(i32x2*)&Alds[s & 1][sc >> 3][sr][sc & 7] = (i32x2){(int)lo, (int)hi};
    const int sn = (s < 15) ? s + 1 : 15;
    if (s < 15) hcur = *(const f32x4*)(hrow + sn * 32);
    __syncthreads();
    i32x4 bnxt[4];
    #pragma unroll
    for (int cf = 0; cf < 4; ++cf) bnxt[cf] = *(const i32x4*)(wp[cf] + sn * 32);
    i32x4 af[4];
    #pragma unroll
    for (int fr = 0; fr < 4; ++fr) af[fr] = *(const i32x4*)&Alds[s & 1][kq][fr*16 + fl][0];
    #pragma unroll
    for (int fr = 0; fr < 4; ++fr)
      #pragma unroll
      for (int cf = 0; cf < 4; ++cf)
        mfma_bf16_16x16x32(acc[fr][cf], af[fr], bcur[cf]);
    #pragma unroll
    for (int cf = 0; cf < 4; ++cf) bcur[cf] = bnxt[cf];
  }

  asm volatile("s_nop 7\ns_nop 7\ns_nop 7" :::);
  const int il0 = kq * 4;
  #pragma unroll
  for (int fr = 0; fr < 4; ++fr) {
    #pragma unroll
    for (int cf = 0; cf < 4; ++cf) {
      const f32x4 v = acc[fr][cf];
      const int f = w*64 + cf*16 + fl;
      const int n = nb + fr*16 + il0;
      unsigned long long pk = (unsigned long long)packbf2(v.x, v.y)
                            | ((unsigned long long)packbf2(v.z, v.w) << 32);
      *(unsigned long long*)(whT + (size_t)(b*512 + f) * 2048 + n) = pk;
    }
  }
}

// ---------------- Kernel D: fused mask+exp+PV+normalize+elu -------------------------------
// 256 blocks (b, i-tile of 64), 512 thr (8 waves; wave w owns f-cols [w*64,w*64+64)).
// Per j-step of 32: P tile (64x32 bf16, dbuf LDS) computed by all threads; 16 MFMA/wave.
__global__ __launch_bounds__(512, 2) void k_attn(const int* __restrict__ adj,
                                                 const unsigned short* __restrict__ whT,
                                                 const float* __restrict__ ei, const float* __restrict__ ej,
                                                 float* __restrict__ out) {
  const int tid = threadIdx.x;
  const int w = tid >> 6, l = tid & 63;
  const int bid = blockIdx.x;
  const int b = bid >> 5;
  const int i0 = (bid & 31) * 64;

  __shared__ __align__(16) unsigned short Plds[2][64][40];
  __shared__ __align__(16) float ejl[2048];
  __shared__ __align__(16) float eil[64];
  __shared__ __align__(16) float llds[64];

  for (int idx = tid; idx < 2048; idx += 512) ejl[idx] = ej[b*2048 + idx];
  if (tid < 64) eil[tid] = ei[b*2048 + i0 + tid];
  __syncthreads();

  const int r = tid >> 4, c2 = tid & 15;       // P-compute role: rows r, r+32; j-pair c2
  const float eir0 = eil[r], eir1 = eil[r + 32];
  const int* adj0 = adj + (size_t)(b*2048 + i0 + r) * 2048 + c2*2;
  const int* adj1 = adj0 + (size_t)32 * 2048;

  const int fl = l & 15, kq = l >> 4;
  const unsigned short* wp[4];
  #pragma unroll
  for (int cf = 0; cf < 4; ++cf) {
    const int f = w*64 + cf*16 + fl;
    wp[cf] = whT + (size_t)(b*512 + f) * 2048 + kq*8;
  }

  f32x4 acc[4][4];
  #pragma unroll
  for (int i = 0; i < 4; ++i)
    #pragma unroll
    for (int j = 0; j < 4; ++j) acc[i][j] = (f32x4){0.f,0.f,0.f,0.f};
  float sum0 = 0.f, sum1 = 0.f;

  i32x2 a0c = *(const i32x2*)(adj0);
  i32x2 a1c = *(const i32x2*)(adj1);
  i32x4 bcur[4];
  #pragma unroll
  for (int cf = 0; cf < 4; ++cf) bcur[cf] = *(const i32x4*)(wp[cf]);

  for (int t = 0; t < 64; ++t) {
    const int tn = (t < 63) ? t + 1 : 63;
    i32x2 a0n = *(const i32x2*)(adj0 + tn*32);
    i32x2 a1n = *(const i32x2*)(adj1 + tn*32);
    i32x4 bnxt[4];
    #pragma unroll
    for (int cf = 0; cf < 4; ++cf) bnxt[cf] = *(const i32x4*)(wp[cf] + tn*32);

    const f32x2 ejv = *(const f32x2*)&ejl[t*32 + c2*2];
    float e00 = eir0 + ejv.x, e01 = eir0 + ejv.y;
    float e10 = eir1 + ejv.x, e11 = eir1 + ejv.y;
    e00 = fmaxf(e00, ALPHA*e00); e01 = fmaxf(e01, ALPHA*e01);   // leaky (log2-domain, commutes)
    e10 = fmaxf(e10, ALPHA*e10); e11 = fmaxf(e11, ALPHA*e11);
    const float p00 = a0c.x ? __builtin_amdgcn_exp2f(e00) : 0.f;
    const float p01 = a0c.y ? __builtin_amdgcn_exp2f(e01) : 0.f;
    const float p10 = a1c.x ? __builtin_amdgcn_exp2f(e10) : 0.f;
    const float p11 = a1c.y ? __builtin_amdgcn_exp2f(e11) : 0.f;
    sum0 += p00 + p01; sum1 += p10 + p11;
    *(unsigned int*)&Plds[t & 1][r][c2*2]      = packbf2(p00, p01);
    *(unsigned int*)&Plds[t & 1][r + 32][c2*2] = packbf2(p10, p11);
    __syncthreads();

    i32x4 af[4];
    #pragma unroll
    for (int fr = 0; fr < 4; ++fr) af[fr] = *(const i32x4*)&Plds[t & 1][fr*16 + fl][kq*8];
    #pragma unroll
    for (int fr = 0; fr < 4; ++fr)
      #pragma unroll
      for (int cf = 0; cf < 4; ++cf)
        mfma_bf16_16x16x32(acc[fr][cf], af[fr], bcur[cf]);

    #pragma unroll
    for (int cf = 0; cf < 4; ++cf) bcur[cf] = bnxt[cf];
    a0c = a0n; a1c = a1n;
  }

  // row sums -> LDS (16 threads per row share, xor-reduce within 16-lane group)
  #pragma unroll
  for (int off = 1; off < 16; off <<= 1) { sum0 += __shfl_xor(sum0, off); sum1 += __shfl_xor(sum1, off); }
  if (c2 == 0) { llds[r] = sum0; llds[r + 32] = sum1; }
  __syncthreads();
  asm volatile("s_nop 7\ns_nop 7\ns_nop 7" :::);

  #pragma unroll
  for (int fr = 0; fr < 4; ++fr) {
    const f32x4 lv = *(const f32x4*)&llds[fr*16 + kq*4];
    f32x4 inv;
    inv.x = __builtin_amdgcn_rcpf(lv.x); inv.y = __builtin_amdgcn_rcpf(lv.y);
    inv.z = __builtin_amdgcn_rcpf(lv.z); inv.w = __builtin_amdgcn_rcpf(lv.w);
    #pragma unroll
    for (int cf = 0; cf < 4; ++cf) {
      const int f = w*64 + cf*16 + fl;
      float* op = out + (size_t)(b*2048 + i0 + fr*16 + kq*4) * 512 + f;
      const f32x4 v = acc[fr][cf];
      float o0 = v.x * inv.x; o0 = o0 > 0.f ? o0 : __expf(o0) - 1.f; op[0]    = o0;
      float o1 = v.y * inv.y; o1 = o1 > 0.f ? o1 : __expf(o1) - 1.f; op[512]  = o1;
      float o2 = v.z * inv.z; o2 = o2 > 0.f ? o2 : __expf(o2) - 1.f; op[1024] = o2;
      float o3 = v.w * inv.w; o3 = o3 > 0.f ? o3 : __expf(o3) - 1.f; op[1536] = o3;
    }
  }
}

extern "C" void kernel_launch(void* const* d_in, const int* in_sizes, int n_in,
                              void* d_out, int out_size, void* d_ws, size_t ws_size,
                              hipStream_t stream) {
  const float* h  = (const float*)d_in[0];
  const int*  adj = (const int*)d_in[1];
  const float* W  = (const float*)d_in[2];
  const float* a  = (const float*)d_in[3];
  float* out = (float*)d_out;
  char* ws = (char*)d_ws;
  unsigned short* wt  = (unsigned short*)(ws);                       // 512*512*2   = 524288
  unsigned short* whT = (unsigned short*)(ws + 524288);              // 8*512*2048*2 = 16777216
  float* ei = (float*)(ws + 524288 + 16777216);                      // 16384*4
  float* ej = ei + 16384;                                            // 16384*4
  float* v1 = ej + 16384;                                            // 512*4
  float* v2 = v1 + 512;                                              // 512*4  (total ~17.4 MB)

  hipLaunchKernelGGL(k_setup,  dim3(384),  dim3(256), 0, stream, W, a, wt, v1, v2);
  hipLaunchKernelGGL(k_ei_ej,  dim3(4096), dim3(256), 0, stream, h, v1, v2, ei, ej);
  hipLaunchKernelGGL(k_gemm_wh,dim3(256),  dim3(512), 0, stream, h, wt, whT);
  hipLaunchKernelGGL(k_attn,   dim3(256),  dim3(512), 0, stream, adj, whT, ei, ej, out);
}

// Round 2
// 318.430 us; speedup vs baseline: 1.0009x; 1.0009x over previous
//
#include <hip/hip_runtime.h>
#include <hip/hip_bf16.h>

#define ALPHA 0.2f
#define LOG2E 1.44269504088896340736f

typedef float  f32x4 __attribute__((ext_vector_type(4)));
typedef float  f32x2 __attribute__((ext_vector_type(2)));
typedef int    i32x4 __attribute__((ext_vector_type(4)));
typedef int    i32x2 __attribute__((ext_vector_type(2)));

static __device__ __forceinline__ void mfma_bf16_16x16x32(f32x4& c, i32x4 a, i32x4 b) {
  asm("v_mfma_f32_16x16x32_bf16 %0, %1, %2, %0" : "+v"(c) : "v"(a), "v"(b));
}

static __device__ __forceinline__ unsigned short f2bf(float x) {
  __hip_bfloat16 b = __float2bfloat16(x);
  return *reinterpret_cast<unsigned short*>(&b);
}
static __device__ __forceinline__ unsigned int packbf2(float x, float y) {
  return (unsigned int)f2bf(x) | ((unsigned int)f2bf(y) << 16);
}
static __device__ __forceinline__ float dot4(f32x4 a, f32x4 b) {
  return a.x*b.x + a.y*b.y + a.z*b.z + a.w*b.w;
}

// ---------------- Kernel A: Wt[f][k] = bf16(W[k][f]);  v1 = log2e*(W@a1), v2 = log2e*(W@a2)
__global__ __launch_bounds__(256) void k_setup(const float* __restrict__ W, const float* __restrict__ a,
                                               unsigned short* __restrict__ wt,
                                               float* __restrict__ v1, float* __restrict__ v2) {
  const int bid = blockIdx.x, tid = threadIdx.x;
  __shared__ float S[32][33];
  if (bid < 256) {               // 16x16 tiles of 32x32: transpose W -> Wt (bf16)
    const int k0 = (bid >> 4) * 32, f0 = (bid & 15) * 32;
    const int r = tid >> 5, c = tid & 31;
    #pragma unroll
    for (int rr = r; rr < 32; rr += 8) S[rr][c] = W[(size_t)(k0 + rr) * 512 + f0 + c];
    __syncthreads();
    #pragma unroll
    for (int rr = r; rr < 32; rr += 8) wt[(size_t)(f0 + rr) * 512 + k0 + c] = f2bf(S[c][rr]);
  } else {                       // 128 blocks x 4 waves: one wave per k-row of W
    const int kk = (bid - 256) * 4 + (tid >> 6);
    const int l = tid & 63;
    const float* wr = W + (size_t)kk * 512 + l * 8;
    f32x4 w0 = *(const f32x4*)(wr),           w1 = *(const f32x4*)(wr + 4);
    f32x4 p0 = *(const f32x4*)(a + l*8),      p1 = *(const f32x4*)(a + l*8 + 4);
    f32x4 q0 = *(const f32x4*)(a + 512 + l*8),q1 = *(const f32x4*)(a + 512 + l*8 + 4);
    float s1 = dot4(w0,p0) + dot4(w1,p1);
    float s2 = dot4(w0,q0) + dot4(w1,q1);
    #pragma unroll
    for (int off = 1; off < 64; off <<= 1) { s1 += __shfl_xor(s1, off); s2 += __shfl_xor(s2, off); }
    if (l == 0) { v1[kk] = s1 * LOG2E; v2[kk] = s2 * LOG2E; }
  }
}

// ---------------- Kernel C: WhT[b][f][n] = bf16( (h@W)[b][n][f] ), fused ei/ej -------------
// 512 blocks x 512 thr (8 waves, 2 blocks/CU). BM=32 rows, BN=512 (all f), BK=32, 16 steps.
// A staged f32->bf16 in LDS [2][32][36] (36-short pad kills 8-way bank conflict).
// ei/ej computed from the SAME h loads (exact f32 path), k_ei_ej kernel deleted.
__global__ __launch_bounds__(512, 4) void k_gemm_wh(const float* __restrict__ h,
                                                    const unsigned short* __restrict__ wt,
                                                    const float* __restrict__ v1g, const float* __restrict__ v2g,
                                                    unsigned short* __restrict__ whT,
                                                    float* __restrict__ ei, float* __restrict__ ej) {
  const int tid = threadIdx.x;
  const int w = tid >> 6, l = tid & 63;
  const int n0g = blockIdx.x * 32;
  const int b = n0g >> 11;
  const int nb = n0g & 2047;
  __shared__ __align__(16) unsigned short Al[2][32][36];
  __shared__ float v1l[512], v2l[512];
  v1l[tid] = v1g[tid]; v2l[tid] = v2g[tid];

  const int sr = tid >> 4;            // staging row 0..31
  const int sc = (tid & 15) * 2;      // staging k 0..30
  const float* hrow = h + (size_t)(n0g + sr) * 512 + sc;

  const int fl = l & 15, kq = l >> 4;
  const unsigned short* wp[4];
  #pragma unroll
  for (int cf = 0; cf < 4; ++cf) wp[cf] = wt + (size_t)(w*64 + cf*16 + fl) * 512 + kq * 8;

  f32x4 acc[2][4];
  #pragma unroll
  for (int i = 0; i < 2; ++i)
    #pragma unroll
    for (int j = 0; j < 4; ++j) acc[i][j] = (f32x4){0.f,0.f,0.f,0.f};
  float s1 = 0.f, s2 = 0.f;

  f32x2 hcur = __builtin_nontemporal_load((const f32x2*)hrow);
  i32x4 bcur[4];
  #pragma unroll
  for (int cf = 0; cf < 4; ++cf) bcur[cf] = *(const i32x4*)(wp[cf]);
  __syncthreads();   // v1l/v2l ready

  #pragma unroll 2
  for (int s = 0; s < 16; ++s) {
    *(unsigned int*)&Al[s & 1][sr][sc] = packbf2(hcur.x, hcur.y);
    const int sn = (s < 15) ? s + 1 : 15;
    f32x2 hnxt = __builtin_nontemporal_load((const f32x2*)(hrow + sn * 32));
    i32x4 bnxt[4];
    #pragma unroll
    for (int cf = 0; cf < 4; ++cf) bnxt[cf] = *(const i32x4*)(wp[cf] + sn * 32);
    const int k = s*32 + sc;
    s1 += hcur.x * v1l[k] + hcur.y * v1l[k+1];
    s2 += hcur.x * v2l[k] + hcur.y * v2l[k+1];
    __syncthreads();
    i32x4 af[2];
    #pragma unroll
    for (int fr = 0; fr < 2; ++fr) af[fr] = *(const i32x4*)&Al[s & 1][fr*16 + fl][kq*8];
    #pragma unroll
    for (int fr = 0; fr < 2; ++fr)
      #pragma unroll
      for (int cf = 0; cf < 4; ++cf)
        mfma_bf16_16x16x32(acc[fr][cf], af[fr], bcur[cf]);
    #pragma unroll
    for (int cf = 0; cf < 4; ++cf) bcur[cf] = bnxt[cf];
    hcur = hnxt;
  }

  // ei/ej: reduce across the 16 lanes sharing row sr
  #pragma unroll
  for (int off = 1; off < 16; off <<= 1) { s1 += __shfl_xor(s1, off); s2 += __shfl_xor(s2, off); }
  if ((tid & 15) == 0) { ei[n0g + sr] = s1; ej[n0g + sr] = s2; }

  asm volatile("s_nop 7\ns_nop 7\ns_nop 7" :::);
  const int il0 = kq * 4;
  #pragma unroll
  for (int fr = 0; fr < 2; ++fr) {
    #pragma unroll
    for (int cf = 0; cf < 4; ++cf) {
      const f32x4 v = acc[fr][cf];
      const int f = w*64 + cf*16 + fl;
      const int n = nb + fr*16 + il0;
      unsigned long long pk = (unsigned long long)packbf2(v.x, v.y)
                            | ((unsigned long long)packbf2(v.z, v.w) << 32);
      *(unsigned long long*)(whT + (size_t)(b*512 + f) * 2048 + n) = pk;
    }
  }
}

// ---------------- Kernel D: fused mask+exp+PV+normalize+elu -------------------------------
// 256 blocks, 1024 thr (16 waves, 50% occupancy). b = bid&7 -> XCD x owns batch x, so the
// 2 MB WhT[b] slice is L2-resident per XCD. i-tile 64; wave owns 32 f-cols (acc[4][2]).
// adj prefetch depth 3 (HBM ~900cy), whT depth 2 (L2/L3). Nontemporal adj/out.
__global__ __launch_bounds__(1024, 4) void k_attn(const int* __restrict__ adj,
                                                  const unsigned short* __restrict__ whT,
                                                  const float* __restrict__ ei, const float* __restrict__ ej,
                                                  float* __restrict__ out) {
  const int tid = threadIdx.x;
  const int w = tid >> 6, l = tid & 63;
  const int b = blockIdx.x & 7;
  const int i0 = (blockIdx.x >> 3) * 64;

  __shared__ __align__(16) unsigned short Plds[2][64][40];
  __shared__ __align__(16) float ejl[2048];
  __shared__ __align__(16) float eil[64];
  __shared__ __align__(16) float llds[64];

  for (int idx = tid; idx < 2048; idx += 1024) ejl[idx] = ej[b*2048 + idx];
  if (tid < 64) eil[tid] = ei[b*2048 + i0 + tid];
  __syncthreads();

  const int r = tid >> 4, c2 = tid & 15;      // P role: one row r, 2 j's per step
  const float eir = eil[r];
  const int* adj0 = adj + (size_t)(b*2048 + i0 + r) * 2048 + c2*2;

  const int fl = l & 15, kq = l >> 4;
  const unsigned short* wp[2];
  #pragma unroll
  for (int cf = 0; cf < 2; ++cf) wp[cf] = whT + (size_t)(b*512 + w*32 + cf*16 + fl) * 2048 + kq*8;

  f32x4 acc[4][2];
  #pragma unroll
  for (int i = 0; i < 4; ++i)
    #pragma unroll
    for (int j = 0; j < 2; ++j) acc[i][j] = (f32x4){0.f,0.f,0.f,0.f};
  float sum = 0.f;

  i32x2 a0 = __builtin_nontemporal_load((const i32x2*)(adj0));
  i32x2 a1 = __builtin_nontemporal_load((const i32x2*)(adj0 + 32));
  i32x2 a2 = __builtin_nontemporal_load((const i32x2*)(adj0 + 64));
  i32x4 b0[2], b1[2];
  #pragma unroll
  for (int cf = 0; cf < 2; ++cf) { b0[cf] = *(const i32x4*)(wp[cf]); b1[cf] = *(const i32x4*)(wp[cf] + 32); }

  #pragma unroll 2
  for (int t = 0; t < 64; ++t) {
    const int t2 = (t + 2 < 64) ? t + 2 : 63;
    const int t3 = (t + 3 < 64) ? t + 3 : 63;
    i32x2 an = __builtin_nontemporal_load((const i32x2*)(adj0 + t3*32));
    i32x4 bn[2];
    #pragma unroll
    for (int cf = 0; cf < 2; ++cf) bn[cf] = *(const i32x4*)(wp[cf] + t2*32);

    const f32x2 ejv = *(const f32x2*)&ejl[t*32 + c2*2];
    float e0 = eir + ejv.x, e1 = eir + ejv.y;
    e0 = fmaxf(e0, ALPHA*e0); e1 = fmaxf(e1, ALPHA*e1);       // leaky (log2-domain, commutes)
    const float p0 = a0.x ? __builtin_amdgcn_exp2f(e0) : 0.f;
    const float p1 = a0.y ? __builtin_amdgcn_exp2f(e1) : 0.f;
    sum += p0 + p1;
    *(unsigned int*)&Plds[t & 1][r][c2*2] = packbf2(p0, p1);
    __syncthreads();

    i32x4 af[4];
    #pragma unroll
    for (int fr = 0; fr < 4; ++fr) af[fr] = *(const i32x4*)&Plds[t & 1][fr*16 + fl][kq*8];
    #pragma unroll
    for (int fr = 0; fr < 4; ++fr)
      #pragma unroll
      for (int cf = 0; cf < 2; ++cf)
        mfma_bf16_16x16x32(acc[fr][cf], af[fr], b0[cf]);

    #pragma unroll
    for (int cf = 0; cf < 2; ++cf) { b0[cf] = b1[cf]; b1[cf] = bn[cf]; }
    a0 = a1; a1 = a2; a2 = an;
  }

  #pragma unroll
  for (int off = 1; off < 16; off <<= 1) sum += __shfl_xor(sum, off);
  if (c2 == 0) llds[r] = sum;
  __syncthreads();
  asm volatile("s_nop 7\ns_nop 7\ns_nop 7" :::);

  #pragma unroll
  for (int fr = 0; fr < 4; ++fr) {
    const f32x4 lv = *(const f32x4*)&llds[fr*16 + kq*4];
    f32x4 inv;
    inv.x = __builtin_amdgcn_rcpf(lv.x); inv.y = __builtin_amdgcn_rcpf(lv.y);
    inv.z = __builtin_amdgcn_rcpf(lv.z); inv.w = __builtin_amdgcn_rcpf(lv.w);
    #pragma unroll
    for (int cf = 0; cf < 2; ++cf) {
      const int f = w*32 + cf*16 + fl;
      float* op = out + (size_t)(b*2048 + i0 + fr*16 + kq*4) * 512 + f;
      const f32x4 v = acc[fr][cf];
      float o0 = v.x * inv.x; o0 = o0 > 0.f ? o0 : __expf(o0) - 1.f;
      float o1 = v.y * inv.y; o1 = o1 > 0.f ? o1 : __expf(o1) - 1.f;
      float o2 = v.z * inv.z; o2 = o2 > 0.f ? o2 : __expf(o2) - 1.f;
      float o3 = v.w * inv.w; o3 = o3 > 0.f ? o3 : __expf(o3) - 1.f;
      __builtin_nontemporal_store(o0, op);
      __builtin_nontemporal_store(o1, op + 512);
      __builtin_nontemporal_store(o2, op + 1024);
      __builtin_nontemporal_store(o3, op + 1536);
    }
  }
}

extern "C" void kernel_launch(void* const* d_in, const int* in_sizes, int n_in,
                              void* d_out, int out_size, void* d_ws, size_t ws_size,
                              hipStream_t stream) {
  const float* h  = (const float*)d_in[0];
  const int*  adj = (const int*)d_in[1];
  const float* W  = (const float*)d_in[2];
  const float* a  = (const float*)d_in[3];
  float* out = (float*)d_out;
  char* ws = (char*)d_ws;
  unsigned short* wt  = (unsigned short*)(ws);                       // 512*512*2   = 524288
  unsigned short* whT = (unsigned short*)(ws + 524288);              // 8*512*2048*2 = 16777216
  float* ei = (float*)(ws + 524288 + 16777216);                      // 16384*4
  float* ej = ei + 16384;                                            // 16384*4
  float* v1 = ej + 16384;                                            // 512*4
  float* v2 = v1 + 512;                                              // 512*4

  hipLaunchKernelGGL(k_setup,   dim3(384), dim3(256),  0, stream, W, a, wt, v1, v2);
  hipLaunchKernelGGL(k_gemm_wh, dim3(512), dim3(512),  0, stream, h, wt, v1, v2, whT, ei, ej);
  hipLaunchKernelGGL(k_attn,    dim3(256), dim3(1024), 0, stream, adj, whT, ei, ej, out);
}